// Round 18
// baseline (318.412 us; speedup 1.0000x reference)
//
#include <hip/hip_runtime.h>
#include <stdint.h>
#include <stddef.h>

// ---------------------------------------------------------------------------
// AttentionLayer: x[4,2048,1024] f32, W_qkv[3072,1024], b_qkv[3072],
//                 W_proj[1024,1024], b_proj[1024]  -> out[4,2048,1024] f32
// gf: 128x128 tile, BK=64, 4 waves. B-operand read DIRECTLY from global
// (L2-resident panels) into MFMA fragments via plain C++ loads (compiler-
// managed waitcnts — no inline asm in the loop). Only A is LDS-staged
// (34.8KB -> 3 blocks/CU). Halves LDS traffic per tile vs r17.
// Fusions unchanged: merged QKV (V-cols -> V^T transposed epilogue), QK^T
// exp(s/32), PV ones-MFMA rowsum + divide, fused cast. 5 dispatches.
// ---------------------------------------------------------------------------

typedef __attribute__((ext_vector_type(8))) short bf16x8;
typedef __attribute__((ext_vector_type(4))) float f32x4;

__device__ __forceinline__ unsigned short f2bf(float f) {
  unsigned u = __float_as_uint(f);
  u += 0x7fffu + ((u >> 16) & 1u);
  return (unsigned short)(u >> 16);
}
__device__ __forceinline__ float bf2f(unsigned short h) {
  return __uint_as_float(((unsigned)h) << 16);
}

typedef const __attribute__((address_space(1))) void* gas_ptr;
typedef __attribute__((address_space(3))) void* las_ptr;

__device__ __forceinline__ void gload_lds16(const void* g, void* l) {
  __builtin_amdgcn_global_load_lds((gas_ptr)(uintptr_t)g,
                                   (las_ptr)(uint32_t)(uintptr_t)l, 16, 0, 0);
}

__device__ __forceinline__ f32x4 mfma16(bf16x8 a, bf16x8 b, f32x4 c) {
  return __builtin_amdgcn_mfma_f32_16x16x32_bf16(a, b, c, 0, 0, 0);
}

// ----------------- fused fp32 -> bf16 cast (x, Wqkv, Wproj) ----------------
__global__ __launch_bounds__(256) void cvt_all(
    const float* __restrict__ x, unsigned short* __restrict__ xo,
    const float* __restrict__ wq, unsigned short* __restrict__ wqo,
    const float* __restrict__ wp, unsigned short* __restrict__ wpo) {
  const int NX = 8388608, NQ = 3145728, NP = 1048576;
  int i = (blockIdx.x * blockDim.x + threadIdx.x) * 4;
  int stride = gridDim.x * blockDim.x * 4;
  for (; i < NX + NQ + NP; i += stride) {
    const float* src;
    unsigned short* dst;
    int off;
    if (i < NX) { src = x; dst = xo; off = i; }
    else if (i < NX + NQ) { src = wq; dst = wqo; off = i - NX; }
    else { src = wp; dst = wpo; off = i - NX - NQ; }
    float4 v = *reinterpret_cast<const float4*>(src + off);
    ushort4 o;
    o.x = f2bf(v.x); o.y = f2bf(v.y); o.z = f2bf(v.z); o.w = f2bf(v.w);
    *reinterpret_cast<ushort4*>(dst + off) = o;
  }
}

// ================================ gf =======================================
// A tile [128][64] bf16 staged in LDS (16KB/buf, swizzled); B read direct.
__device__ __forceinline__ void stage_A(const unsigned short* __restrict__ P,
                                        int ld, unsigned short* dst, int wid,
                                        int lane) {
#pragma unroll
  for (int c = 0; c < 4; ++c) {
    int s = (c * 4 + wid) * 64 + lane;
    int row = s >> 3, g = s & 7;
    gload_lds16(P + (size_t)row * ld + ((g ^ (row & 7)) * 8),
                dst + (c * 4 + wid) * 512);
  }
}

// QKV: merged projection; cols<2048 -> Cv (qk), cols>=2048 -> Cv2 = V^T.
// RINV: rowsum(A) via ones-MFMA; epilogue multiplies by 1/rowsum.
template <bool OUT_BF16, bool HAS_BIAS, bool EXPOUT, bool RINV, bool QKV>
__global__ __launch_bounds__(256, 3) void gf(
    const unsigned short* __restrict__ A, const unsigned short* __restrict__ B,
    void* __restrict__ Cv, void* __restrict__ Cv2,
    const float* __restrict__ bias,
    int K, int lda, int ldb, int ldc,
    long long strideA, long long strideB, long long strideC, float alpha) {
  __shared__ unsigned short lds[2][8704];  // 34816B; 16KB stage per buf

  const int bz = blockIdx.z;
  const int gx = gridDim.x;
  int lin = blockIdx.y * gx + blockIdx.x;
  int bx, by;
  {
    const int nwg = gx * gridDim.y;
    const int q = nwg >> 3;                 // XCD chunking (nwg % 8 == 0)
    lin = (lin & 7) * q + (lin >> 3);
    const int t = lin >> 6, r = lin & 63;   // 8x8 tile ordering per 64 blocks
    const int tilesX = gx >> 3;
    bx = (t % tilesX) * 8 + (r & 7);
    by = (t / tilesX) * 8 + (r >> 3);
  }
  const int rowBase = by * 128;
  const int colBase = bx * 128;

  const unsigned short* Ap = A + (size_t)bz * (size_t)strideA + (size_t)rowBase * lda;
  const unsigned short* Bp = B + (size_t)bz * (size_t)strideB + (size_t)colBase * ldb;

  const int tid = threadIdx.x;
  const int wid = tid >> 6;
  const int lane = tid & 63;
  const int wr = wid >> 1;
  const int wc = wid & 1;
  const int fr = lane & 15;
  const int kgi = lane >> 4;

  const int nt = K >> 6;

  f32x4 acc[4][4] = {};
  f32x4 rsacc[4] = {};
  bf16x8 ones;
#pragma unroll
  for (int i = 0; i < 8; ++i) ones[i] = (short)0x3F80;  // bf16 1.0

  // per-lane B fragment row pointers (16B-aligned, K-contiguous reads)
  const unsigned short* Brow[4];
#pragma unroll
  for (int n = 0; n < 4; ++n)
    Brow[n] = Bp + (size_t)(wc * 64 + n * 16 + fr) * ldb + kgi * 8;

  // prologue: stage A(0); syncthreads drains it
  stage_A(Ap, lda, &lds[0][0], wid, lane);
  __syncthreads();

  for (int t = 0; t < nt; ++t) {
    const int cur = t & 1;
    if (t + 1 < nt)
      stage_A(Ap + (size_t)(t + 1) * 64, lda, &lds[cur ^ 1][0], wid, lane);

    // B fragments for tile t — plain loads; compiler inserts the waitcnts.
    const int k0 = t * 64;
    bf16x8 bv[4][2];
#pragma unroll
    for (int n = 0; n < 4; ++n) {
      bv[n][0] = *(const bf16x8*)(Brow[n] + k0);
      bv[n][1] = *(const bf16x8*)(Brow[n] + k0 + 32);
    }

    const unsigned short* sAc = &lds[cur][0];
    bf16x8 af[4][2];
#pragma unroll
    for (int m = 0; m < 4; ++m) {
      int row = wr * 64 + m * 16 + fr;
      int r7 = row & 7;
      af[m][0] = *(const bf16x8*)&sAc[row * 64 + ((kgi ^ r7) * 8)];
      af[m][1] = *(const bf16x8*)&sAc[row * 64 + (((4 + kgi) ^ r7) * 8)];
    }
#pragma unroll
    for (int m = 0; m < 4; ++m)
#pragma unroll
      for (int n = 0; n < 4; ++n) {
        acc[m][n] = mfma16(af[m][0], bv[n][0], acc[m][n]);
        acc[m][n] = mfma16(af[m][1], bv[n][1], acc[m][n]);
      }
    if (RINV) {
#pragma unroll
      for (int m = 0; m < 4; ++m) {
        rsacc[m] = mfma16(af[m][0], ones, rsacc[m]);
        rsacc[m] = mfma16(af[m][1], ones, rsacc[m]);
      }
    }
    __syncthreads();  // drains A-stage(t+1); orders buffer reuse
  }

  // ---- epilogue: C/D layout col=lane&15, row=(lane>>4)*4+j ----
  const int rg = (lane >> 4) * 4;
  const bool doTrans = QKV && (colBase >= 2048);

  if (doTrans) {
    // transposed pack: cl[d][s], padded row 136 shorts (34816B exactly)
    unsigned short* cl = &lds[0][0];
#pragma unroll
    for (int m = 0; m < 4; ++m) {
      int rloc0 = wr * 64 + m * 16 + rg;
#pragma unroll
      for (int n = 0; n < 4; ++n) {
        int cloc = wc * 64 + n * 16 + fr;
        float bvs = HAS_BIAS ? bias[colBase + cloc] : 0.0f;
#pragma unroll
        for (int j = 0; j < 4; ++j) {
          float v = acc[m][n][j] * alpha + bvs;
          cl[cloc * 136 + rloc0 + j] = f2bf(v);
        }
      }
    }
    __syncthreads();
    const int b = rowBase >> 11;
    const int s0 = rowBase & 2047;
    const int dBase = colBase - 2048;
    unsigned short* Vt = reinterpret_cast<unsigned short*>(Cv2);
#pragma unroll
    for (int i = 0; i < 8; ++i) {
      int slot = i * 256 + tid;
      int d = slot >> 4, sg = slot & 15;
      bf16x8 v = *(const bf16x8*)&cl[d * 136 + sg * 8];
      *(bf16x8*)&Vt[((size_t)(b * 1024 + dBase + d)) * 2048 + s0 + sg * 8] = v;
    }
  } else if (OUT_BF16) {
    unsigned short* cl = &lds[0][0];  // 32KB of 34.8KB
#pragma unroll
    for (int m = 0; m < 4; ++m) {
      int rloc0 = wr * 64 + m * 16 + rg;
      float rs4[4];
      if (RINV) {
#pragma unroll
        for (int j = 0; j < 4; ++j) rs4[j] = 1.0f / rsacc[m][j];
      }
#pragma unroll
      for (int n = 0; n < 4; ++n) {
        int cloc = wc * 64 + n * 16 + fr;
        float bvs = 0.0f;
        if (HAS_BIAS) bvs = bias[colBase + cloc];
#pragma unroll
        for (int j = 0; j < 4; ++j) {
          int row = rloc0 + j;
          float v = acc[m][n][j] * alpha;
          if (EXPOUT) v = __expf(v);
          else v += bvs;
          if (RINV) v *= rs4[j];
          int gW = cloc >> 3;
          int gS = (gW & 8) | ((gW & 7) ^ (row & 7));
          cl[row * 128 + gS * 8 + (cloc & 7)] = f2bf(v);
        }
      }
    }
    __syncthreads();
    unsigned short* Cb =
        reinterpret_cast<unsigned short*>(Cv) + (size_t)bz * (size_t)strideC;
#pragma unroll
    for (int i = 0; i < 8; ++i) {
      int slot = i * 256 + tid;
      int row = slot >> 4, g = slot & 15;
      int gS = (g & 8) | ((g & 7) ^ (row & 7));
      bf16x8 v = *(const bf16x8*)&cl[row * 128 + gS * 8];
      *(bf16x8*)&Cb[(size_t)(rowBase + row) * ldc + colBase + g * 8] = v;
    }
  } else {
    // f32 path: two 64-row halves through 32KB of LDS, coalesced float4 out
    float* clf = reinterpret_cast<float*>(&lds[0][0]);
    float* Cf = reinterpret_cast<float*>(Cv) + (size_t)bz * (size_t)strideC;
#pragma unroll
    for (int half = 0; half < 2; ++half) {
      if (wr == half) {
#pragma unroll
        for (int m = 0; m < 4; ++m) {
          int rloc0 = m * 16 + rg;
#pragma unroll
          for (int n = 0; n < 4; ++n) {
            int cloc = wc * 64 + n * 16 + fr;
            float bvs = 0.0f;
            if (HAS_BIAS) bvs = bias[colBase + cloc];
#pragma unroll
            for (int j = 0; j < 4; ++j) {
              float v = acc[m][n][j] * alpha + bvs;
              clf[(rloc0 + j) * 128 + cloc] = v;
            }
          }
        }
      }
      __syncthreads();
#pragma unroll
      for (int i = 0; i < 8; ++i) {
        int slot = i * 256 + tid;          // 64 rows x 32 float4-groups
        int row = slot >> 5, g = slot & 31;
        float4 v = *(const float4*)&clf[row * 128 + g * 4];
        *(float4*)&Cf[(size_t)(rowBase + half * 64 + row) * ldc + colBase + g * 4] = v;
      }
      __syncthreads();
    }
  }
}

// ---------------------------------------------------------------------------
extern "C" void kernel_launch(void* const* d_in, const int* in_sizes, int n_in,
                              void* d_out, int out_size, void* d_ws, size_t ws_size,
                              hipStream_t stream) {
  const float* x     = (const float*)d_in[0];
  const float* Wqkv  = (const float*)d_in[1];
  const float* bqkv  = (const float*)d_in[2];
  const float* Wproj = (const float*)d_in[3];
  const float* bproj = (const float*)d_in[4];
  float* out = (float*)d_out;

  char* ws = (char*)d_ws;
  unsigned short* qk   = (unsigned short*)(ws + 0);          // 8192x2048 bf16
  unsigned short* xatt = (unsigned short*)(ws + 50331648);   // 8192x1024 bf16
  unsigned short* wq   = (unsigned short*)(ws + 67108864);   // 3072x1024 bf16
  unsigned short* wp   = (unsigned short*)(ws + 73400320);   // 1024x1024 bf16
  unsigned short* vt   = (unsigned short*)(ws + 75497472);   // 4x1024x2048 bf16
  unsigned short* sc   = (unsigned short*)(ws + 92274688);   // 4x2048x2048 bf16

  dim3 blk256(256);

  // 1. fused casts
  cvt_all<<<3072, blk256, 0, stream>>>(x, xatt, Wqkv, wq, Wproj, wp);

  // 2. merged QKV projection: N=3072 (grid 24x64 = 1536).
  //    cols<2048 -> qk; cols>=2048 -> V^T (vt).
  gf<true, true, false, false, true><<<dim3(24, 64, 1), blk256, 0, stream>>>(
      xatt, wq, qk, vt, bqkv,
      1024, 1024, 1024, 2048, 0, 0, 0, 1.0f);

  // 3. P~ = exp(Q @ K^T / 32)  (grid 16x16x4 = 1024)
  gf<true, false, true, false, false><<<dim3(16, 16, 4), blk256, 0, stream>>>(
      qk, qk + 1024, sc, nullptr, nullptr,
      1024, 2048, 2048, 2048,
      2048LL * 2048, 2048LL * 2048, 2048LL * 2048, 0.03125f);

  // 4. attn_out = (P~ @ Vt) / rowsum(P~)  (grid 8x16x4 = 512)
  gf<true, false, false, true, false><<<dim3(8, 16, 4), blk256, 0, stream>>>(
      sc, vt, xatt, nullptr, nullptr,
      2048, 2048, 2048, 1024,
      2048LL * 2048, 1024LL * 2048, 2048LL * 1024, 1.0f);

  // 5. out = attn_out @ Wproj^T + b_proj  (grid 8x64 = 512)
  gf<false, true, false, false, false><<<dim3(8, 64, 1), blk256, 0, stream>>>(
      xatt, wp, out, nullptr, bproj,
      1024, 1024, 1024, 1024, 0, 0, 0, 1.0f);
}

// Round 19
// 170.241 us; speedup vs baseline: 1.8704x; 1.8704x over previous
//
#include <hip/hip_runtime.h>
#include <stdint.h>
#include <stddef.h>

// ---------------------------------------------------------------------------
// AttentionLayer: x[4,2048,1024] f32, W_qkv[3072,1024], b_qkv[3072],
//                 W_proj[1024,1024], b_proj[1024]  -> out[4,2048,1024] f32
// FINAL: Round-13/15/17 configuration (170.4 us, reproduced three times).
// Uniform GEMM "gf": 128x128 tile, BK=64, 4 waves, 1 barrier/K-tile, 64KB LDS
// dbuf -> 2 blocks/CU, XCD chunking + 8x8 L2 block-tiling.
// Fusions: ONE merged QKV dispatch (N=3072; V-columns epilogue writes V^T
// directly); QK^T writes exp(s/32); PV computes rowsums via ones-MFMA and
// divides in epilogue; ONE fused cast kernel. 5 dispatches total.
// Refuted alternatives (this session): 256^2 tiles (1 blk/CU latency),
// BK=32 rings, counted-vmcnt ring-4, no-asm scheduling, B-direct-from-L2.
// ---------------------------------------------------------------------------

typedef __attribute__((ext_vector_type(8))) short bf16x8;
typedef __attribute__((ext_vector_type(4))) float f32x4;

__device__ __forceinline__ unsigned short f2bf(float f) {
  unsigned u = __float_as_uint(f);
  u += 0x7fffu + ((u >> 16) & 1u);
  return (unsigned short)(u >> 16);
}
__device__ __forceinline__ float bf2f(unsigned short h) {
  return __uint_as_float(((unsigned)h) << 16);
}

typedef const __attribute__((address_space(1))) void* gas_ptr;
typedef __attribute__((address_space(3))) void* las_ptr;

__device__ __forceinline__ void gload_lds16(const void* g, void* l) {
  __builtin_amdgcn_global_load_lds((gas_ptr)(uintptr_t)g,
                                   (las_ptr)(uint32_t)(uintptr_t)l, 16, 0, 0);
}

__device__ __forceinline__ f32x4 mfma16(bf16x8 a, bf16x8 b, f32x4 c) {
  return __builtin_amdgcn_mfma_f32_16x16x32_bf16(a, b, c, 0, 0, 0);
}

// ----------------- fused fp32 -> bf16 cast (x, Wqkv, Wproj) ----------------
__global__ __launch_bounds__(256) void cvt_all(
    const float* __restrict__ x, unsigned short* __restrict__ xo,
    const float* __restrict__ wq, unsigned short* __restrict__ wqo,
    const float* __restrict__ wp, unsigned short* __restrict__ wpo) {
  const int NX = 8388608, NQ = 3145728, NP = 1048576;  // elems
  int i = (blockIdx.x * blockDim.x + threadIdx.x) * 4;
  int stride = gridDim.x * blockDim.x * 4;
  for (; i < NX + NQ + NP; i += stride) {
    const float* src;
    unsigned short* dst;
    int off;
    if (i < NX) { src = x; dst = xo; off = i; }
    else if (i < NX + NQ) { src = wq; dst = wqo; off = i - NX; }
    else { src = wp; dst = wpo; off = i - NX - NQ; }
    float4 v = *reinterpret_cast<const float4*>(src + off);
    ushort4 o;
    o.x = f2bf(v.x); o.y = f2bf(v.y); o.z = f2bf(v.z); o.w = f2bf(v.w);
    *reinterpret_cast<ushort4*>(dst + off) = o;
  }
}

// ================================ gf =======================================
__device__ __forceinline__ void stage_gf(const unsigned short* __restrict__ P,
                                         int ld, unsigned short* dst, int wid,
                                         int lane) {
#pragma unroll
  for (int c = 0; c < 4; ++c) {
    int s = (c * 4 + wid) * 64 + lane;
    int row = s >> 3, g = s & 7;
    gload_lds16(P + (size_t)row * ld + ((g ^ (row & 7)) * 8),
                dst + (c * 4 + wid) * 512);
  }
}

// QKV: merged projection; cols<2048 -> Cv (qk, ldc), cols>=2048 -> Cv2 = V^T.
// RINV: accumulate rowsum(A) via ones-MFMA; epilogue multiplies by 1/rowsum.
template <bool OUT_BF16, bool HAS_BIAS, bool EXPOUT, bool RINV, bool QKV>
__global__ __launch_bounds__(256, 2) void gf(
    const unsigned short* __restrict__ A, const unsigned short* __restrict__ B,
    void* __restrict__ Cv, void* __restrict__ Cv2,
    const float* __restrict__ bias,
    int K, int lda, int ldb, int ldc,
    long long strideA, long long strideB, long long strideC, float alpha) {
  __shared__ unsigned short lds[2][2][128 * 64];  // 64KB

  const int bz = blockIdx.z;
  const int gx = gridDim.x;
  int lin = blockIdx.y * gx + blockIdx.x;
  int bx, by;
  {
    const int nwg = gx * gridDim.y;
    const int q = nwg >> 3;                 // XCD chunking (nwg % 8 == 0)
    lin = (lin & 7) * q + (lin >> 3);
    const int t = lin >> 6, r = lin & 63;   // 8x8 tile ordering per 64 blocks
    const int tilesX = gx >> 3;
    bx = (t % tilesX) * 8 + (r & 7);
    by = (t / tilesX) * 8 + (r >> 3);
  }
  const int rowBase = by * 128;
  const int colBase = bx * 128;

  const unsigned short* Ap = A + (size_t)bz * (size_t)strideA + (size_t)rowBase * lda;
  const unsigned short* Bp = B + (size_t)bz * (size_t)strideB + (size_t)colBase * ldb;

  const int tid = threadIdx.x;
  const int wid = tid >> 6;
  const int lane = tid & 63;
  const int wr = wid >> 1;
  const int wc = wid & 1;
  const int fr = lane & 15;
  const int kgi = lane >> 4;

  const int nt = K >> 6;

  f32x4 acc[4][4] = {};
  f32x4 rsacc[4] = {};
  bf16x8 ones;
#pragma unroll
  for (int i = 0; i < 8; ++i) ones[i] = (short)0x3F80;  // bf16 1.0

  stage_gf(Ap, lda, &lds[0][0][0], wid, lane);
  stage_gf(Bp, ldb, &lds[0][1][0], wid, lane);
  asm volatile("s_waitcnt vmcnt(0)" ::: "memory");
  __builtin_amdgcn_sched_barrier(0);
  __builtin_amdgcn_s_barrier();

  for (int t = 0; t < nt; ++t) {
    const int cur = t & 1;
    if (t + 1 < nt) {
      stage_gf(Ap + (size_t)(t + 1) * 64, lda, &lds[cur ^ 1][0][0], wid, lane);
      stage_gf(Bp + (size_t)(t + 1) * 64, ldb, &lds[cur ^ 1][1][0], wid, lane);
    }
    const unsigned short* sAc = &lds[cur][0][0];
    const unsigned short* sBc = &lds[cur][1][0];

    bf16x8 af[4][2], bv[4][2];
#pragma unroll
    for (int m = 0; m < 4; ++m) {
      int row = wr * 64 + m * 16 + fr;
      int r7 = row & 7;
      af[m][0] = *(const bf16x8*)&sAc[row * 64 + ((kgi ^ r7) * 8)];
      af[m][1] = *(const bf16x8*)&sAc[row * 64 + (((4 + kgi) ^ r7) * 8)];
    }
#pragma unroll
    for (int n = 0; n < 4; ++n) {
      int row = wc * 64 + n * 16 + fr;
      int r7 = row & 7;
      bv[n][0] = *(const bf16x8*)&sBc[row * 64 + ((kgi ^ r7) * 8)];
      bv[n][1] = *(const bf16x8*)&sBc[row * 64 + (((4 + kgi) ^ r7) * 8)];
    }
    asm volatile("s_waitcnt lgkmcnt(0)" ::: "memory");
    __builtin_amdgcn_sched_barrier(0);
    __builtin_amdgcn_s_setprio(1);
#pragma unroll
    for (int m = 0; m < 4; ++m)
#pragma unroll
      for (int n = 0; n < 4; ++n) {
        acc[m][n] = mfma16(af[m][0], bv[n][0], acc[m][n]);
        acc[m][n] = mfma16(af[m][1], bv[n][1], acc[m][n]);
      }
    if (RINV) {
#pragma unroll
      for (int m = 0; m < 4; ++m) {
        rsacc[m] = mfma16(af[m][0], ones, rsacc[m]);
        rsacc[m] = mfma16(af[m][1], ones, rsacc[m]);
      }
    }
    __builtin_amdgcn_s_setprio(0);
    __builtin_amdgcn_sched_barrier(0);
    asm volatile("s_waitcnt vmcnt(0)" ::: "memory");
    __builtin_amdgcn_sched_barrier(0);
    __builtin_amdgcn_s_barrier();
  }

  // ---- epilogue: C/D layout col=lane&15, row=(lane>>4)*4+j ----
  const int rg = (lane >> 4) * 4;
  const bool doTrans = QKV && (colBase >= 2048);

  if (doTrans) {
    // transposed pack: cl[d][s], padded row 136 shorts; V^T output
    unsigned short* cl = &lds[0][0][0];
#pragma unroll
    for (int m = 0; m < 4; ++m) {
      int rloc0 = wr * 64 + m * 16 + rg;
#pragma unroll
      for (int n = 0; n < 4; ++n) {
        int cloc = wc * 64 + n * 16 + fr;
        float bvs = HAS_BIAS ? bias[colBase + cloc] : 0.0f;
#pragma unroll
        for (int j = 0; j < 4; ++j) {
          float v = acc[m][n][j] * alpha + bvs;
          cl[cloc * 136 + rloc0 + j] = f2bf(v);
        }
      }
    }
    __syncthreads();
    const int b = rowBase >> 11;
    const int s0 = rowBase & 2047;
    const int dBase = colBase - 2048;
    unsigned short* Vt = reinterpret_cast<unsigned short*>(Cv2);
#pragma unroll
    for (int i = 0; i < 8; ++i) {
      int slot = i * 256 + tid;
      int d = slot >> 4, sg = slot & 15;
      bf16x8 v = *(const bf16x8*)&cl[d * 136 + sg * 8];
      *(bf16x8*)&Vt[((size_t)(b * 1024 + dBase + d)) * 2048 + s0 + sg * 8] = v;
    }
  } else if (OUT_BF16) {
    unsigned short* cl = &lds[0][0][0];
#pragma unroll
    for (int m = 0; m < 4; ++m) {
      int rloc0 = wr * 64 + m * 16 + rg;
      float rs4[4];
      if (RINV) {
#pragma unroll
        for (int j = 0; j < 4; ++j) rs4[j] = 1.0f / rsacc[m][j];
      }
#pragma unroll
      for (int n = 0; n < 4; ++n) {
        int cloc = wc * 64 + n * 16 + fr;
        float bvs = 0.0f;
        if (HAS_BIAS) bvs = bias[colBase + cloc];
#pragma unroll
        for (int j = 0; j < 4; ++j) {
          int row = rloc0 + j;
          float v = acc[m][n][j] * alpha;
          if (EXPOUT) v = __expf(v);
          else v += bvs;
          if (RINV) v *= rs4[j];
          int gW = cloc >> 3;
          int gS = (gW & 8) | ((gW & 7) ^ (row & 7));
          cl[row * 128 + gS * 8 + (cloc & 7)] = f2bf(v);
        }
      }
    }
    __syncthreads();
    unsigned short* Cb =
        reinterpret_cast<unsigned short*>(Cv) + (size_t)bz * (size_t)strideC;
#pragma unroll
    for (int i = 0; i < 8; ++i) {
      int slot = i * 256 + tid;
      int row = slot >> 4, g = slot & 15;
      int gS = (g & 8) | ((g & 7) ^ (row & 7));
      bf16x8 v = *(const bf16x8*)&cl[row * 128 + gS * 8];
      *(bf16x8*)&Cb[(size_t)(rowBase + row) * ldc + colBase + g * 8] = v;
    }
  } else {
    float* clf = reinterpret_cast<float*>(&lds[0][0][0]);
#pragma unroll
    for (int m = 0; m < 4; ++m) {
      int rloc0 = wr * 64 + m * 16 + rg;
#pragma unroll
      for (int n = 0; n < 4; ++n) {
        int cloc = wc * 64 + n * 16 + fr;
        float bvs = 0.0f;
        if (HAS_BIAS) bvs = bias[colBase + cloc];
#pragma unroll
        for (int j = 0; j < 4; ++j) {
          int row = rloc0 + j;
          float v = acc[m][n][j] * alpha + bvs;
          int gW = cloc >> 2;
          int gS = (gW & 24) | ((gW & 7) ^ (row & 7));
          clf[row * 128 + gS * 4 + (cloc & 3)] = v;
        }
      }
    }
    __syncthreads();
    float* Cf = reinterpret_cast<float*>(Cv) + (size_t)bz * (size_t)strideC;
#pragma unroll
    for (int i = 0; i < 16; ++i) {
      int slot = i * 256 + tid;
      int row = slot >> 5, g = slot & 31;
      int gS = (g & 24) | ((g & 7) ^ (row & 7));
      float4 v = *(const float4*)&clf[row * 128 + gS * 4];
      *(float4*)&Cf[(size_t)(rowBase + row) * ldc + colBase + g * 4] = v;
    }
  }
}

// ---------------------------------------------------------------------------
extern "C" void kernel_launch(void* const* d_in, const int* in_sizes, int n_in,
                              void* d_out, int out_size, void* d_ws, size_t ws_size,
                              hipStream_t stream) {
  const float* x     = (const float*)d_in[0];
  const float* Wqkv  = (const float*)d_in[1];
  const float* bqkv  = (const float*)d_in[2];
  const float* Wproj = (const float*)d_in[3];
  const float* bproj = (const float*)d_in[4];
  float* out = (float*)d_out;

  char* ws = (char*)d_ws;
  unsigned short* qk   = (unsigned short*)(ws + 0);          // 8192x2048 bf16
  unsigned short* xatt = (unsigned short*)(ws + 50331648);   // 8192x1024 bf16
  unsigned short* wq   = (unsigned short*)(ws + 67108864);   // 3072x1024 bf16
  unsigned short* wp   = (unsigned short*)(ws + 73400320);   // 1024x1024 bf16
  unsigned short* vt   = (unsigned short*)(ws + 75497472);   // 4x1024x2048 bf16
  unsigned short* sc   = (unsigned short*)(ws + 92274688);   // 4x2048x2048 bf16

  dim3 blk256(256);

  // 1. fused casts
  cvt_all<<<3072, blk256, 0, stream>>>(x, xatt, Wqkv, wq, Wproj, wp);

  // 2. merged QKV projection: N=3072 (grid 24x64 = 1536 = 3 exact rounds).
  //    cols<2048 -> qk; cols>=2048 -> V^T (vt).
  gf<true, true, false, false, true><<<dim3(24, 64, 1), blk256, 0, stream>>>(
      xatt, wq, qk, vt, bqkv,
      1024, 1024, 1024, 2048, 0, 0, 0, 1.0f);

  // 3. P~ = exp(Q @ K^T / 32)  (grid 16x16x4 = 1024)
  gf<true, false, true, false, false><<<dim3(16, 16, 4), blk256, 0, stream>>>(
      qk, qk + 1024, sc, nullptr, nullptr,
      1024, 2048, 2048, 2048,
      2048LL * 2048, 2048LL * 2048, 2048LL * 2048, 0.03125f);

  // 4. attn_out = (P~ @ Vt) / rowsum(P~)  (grid 8x16x4 = 512)
  gf<true, false, false, true, false><<<dim3(8, 16, 4), blk256, 0, stream>>>(
      sc, vt, xatt, nullptr, nullptr,
      2048, 2048, 2048, 1024,
      2048LL * 2048, 1024LL * 2048, 2048LL * 1024, 1.0f);

  // 5. out = attn_out @ Wproj^T + b_proj  (grid 8x64 = 512)
  gf<false, true, false, false, false><<<dim3(8, 64, 1), blk256, 0, stream>>>(
      xatt, wp, out, nullptr, bproj,
      1024, 1024, 1024, 1024, 0, 0, 0, 1.0f);
}